// Round 2
// baseline (237.494 us; speedup 1.0000x reference)
//
#include <hip/hip_runtime.h>

#define BATCH 512
#define TLEN  2048
#define NST   24
#define ESTR  28          // floats per ctx row in E table: 24 E + lognorm + 3 pad
#define NCTX  100         // ctx = (c2*5 + c1)*4 + c0  (c2,c1 in 0..4, c0 in 0..3)

static_assert(BATCH * NST % 256 == 0, "phaseA packing");

__device__ __forceinline__ unsigned short f2bf(float x) {
  unsigned u = __float_as_uint(x);
  u += 0x7FFFu + ((u >> 16) & 1u);
  return (unsigned short)(u >> 16);
}

// R[dst] = sum over edges (src->dst) of A[edge]*f[src]; edges numbered source-major.
__device__ __forceinline__ void at_update(const float* __restrict__ A,
                                          const float* __restrict__ f,
                                          float* __restrict__ R) {
  R[0]  = A[0]*f[0];
  R[1]  = A[1]*f[0];
  R[2]  = A[2]*f[1];
  R[3]  = A[3]*f[2];
  R[4]  = A[4]*f[3]  + A[24]*f[16];
  R[5]  = A[8]*f[4];
  R[6]  = A[9]*f[5];
  R[7]  = A[6]*f[3]  + A[10]*f[6] + A[28]*f[19];
  R[8]  = A[13]*f[7];
  R[9]  = A[14]*f[8];
  R[10] = A[7]*f[3]  + A[12]*f[6] + A[15]*f[9] + A[32]*f[22];
  R[11] = A[17]*f[10];
  R[12] = A[18]*f[11];
  R[13] = A[19]*f[12] + A[20]*f[13];
  R[14] = A[5]*f[3]  + A[25]*f[16];
  R[15] = A[22]*f[14];
  R[16] = A[23]*f[15];
  R[17] = A[11]*f[6] + A[29]*f[19];
  R[18] = A[26]*f[17];
  R[19] = A[27]*f[18];
  R[20] = A[16]*f[9] + A[33]*f[22];
  R[21] = A[30]*f[20];
  R[22] = A[31]*f[21];
  R[23] = A[21]*f[13] + A[34]*f[23];
}

__device__ __forceinline__ float tree_sum24(const float* a) {
  float s0 = a[0]+a[1],   s1 = a[2]+a[3],   s2 = a[4]+a[5],   s3 = a[6]+a[7];
  float s4 = a[8]+a[9],   s5 = a[10]+a[11], s6 = a[12]+a[13], s7 = a[14]+a[15];
  float s8 = a[16]+a[17], s9 = a[18]+a[19], s10= a[20]+a[21], s11= a[22]+a[23];
  float u0 = s0+s1, u1 = s2+s3, u2 = s4+s5, u3 = s6+s7, u4 = s8+s9, u5 = s10+s11;
  return ((u0+u1) + (u2+u3)) + (u4+u5);
}

// ------------------------------------------------------------------
// Builder: A edge values (row softmax) + normalized E table per context.
// ------------------------------------------------------------------
__global__ __launch_bounds__(256) void k_build_tables(
    const float* __restrict__ wt, const float* __restrict__ we,
    float* __restrict__ etab, float* __restrict__ a35out)
{
  __shared__ float lg[NST * 216];
  __shared__ float rmx[NST];
  __shared__ float rrs[NST];
  int tid = threadIdx.x;
  for (int i = tid; i < NST * 216; i += 256) lg[i] = -1e30f;
  __syncthreads();

  for (int e = tid; e < 1073; e += 256) {
    int s, i, j, l, k = -1;
    if (e < 84)        { int ep=e; l=ep&3; int p=ep>>2; if (p<16){i=p>>2;j=p&3;} else {i=4;j=p-16;} s=0; k=ep; }
    else if (e < 104)  { int ep=e-84;  s=1;  i=ep>>2; j=ep&3; l=0; k=84+ep; }
    else if (e < 108)  { int ep=e-104; s=2;  i=ep;    j=0;    l=3; k=104+ep; }
    else if (e < 109)  { s=3; i=0; j=3; l=2; }
    else if (e < 113)  { int ep=e-109; s=4;  i=3; j=2; l=ep;  k=108+ep; }
    else if (e < 129)  { int ep=e-113; s=5;  i=2; j=ep>>2; l=ep&3; k=112+ep; }
    else if (e < 385)  { int ep=e-129; s=6+(ep>>6); int q=ep&63; i=q>>4; j=(q>>2)&3; l=q&3; k=128+ep; }
    else if (e < 401)  { int ep=e-385; s=10; i=ep>>2; j=ep&3; l=3; k=384+ep; }
    else if (e < 405)  { int ep=e-401; s=11; i=ep; j=3; l=0; k=400+ep; }
    else if (e < 409)  { int ep=e-405; s=11; i=ep; j=3; l=2; k=404+ep; }
    else if (e < 412)  { int ep=e-409; s=12; i=3; j=(ep==2)?2:0; l=(ep==1)?2:0; }
    else if (e < 476)  { int ep=e-412; s=13; i=ep>>4; j=(ep>>2)&3; l=ep&3; k=408+ep; }
    else if (e < 1052) { int ep=e-476; s=14+(ep>>6); int q=ep&63; i=q>>4; j=(q>>2)&3; l=q&3; k=472+ep; }
    else if (e < 1068) { int ep=e-1052; s=23; i=ep>>2; j=ep&3; l=5; k=1048+ep; }
    else if (e < 1072) { int ep=e-1068; s=23; i=ep; j=5; l=5; k=1064+ep; }
    else               { s=23; i=5; j=5; l=5; }
    float v = (k < 0) ? 1.0f : we[k];
    lg[s*216 + i*36 + j*6 + l] = v;
  }
  __syncthreads();

  if (tid < NST) {
    float mx = -1e30f;
    for (int x = 0; x < 216; ++x) mx = fmaxf(mx, lg[tid*216 + x]);
    float sum = 0.f;
    for (int x = 0; x < 216; ++x) sum += expf(lg[tid*216 + x] - mx);
    rmx[tid] = mx;
    rrs[tid] = 1.0f / sum;
  }
  __syncthreads();

  if (tid < NCTX) {
    int c2 = tid / 20, c1 = (tid >> 2) % 5, c0 = tid & 3;
    int x = c2*36 + c1*6 + c0;
    float v[NST];
    float m = 1e-30f;
    for (int s = 0; s < NST; ++s) {
      v[s] = expf(lg[s*216 + x] - rmx[s]) * rrs[s];
      m = fmaxf(m, v[s]);
    }
    float im = 1.0f / m;
    for (int s = 0; s < NST; ++s) etab[tid*ESTR + s] = v[s] * im;
    etab[tid*ESTR + 24] = logf(m);
    etab[tid*ESTR + 25] = 0.f; etab[tid*ESTR + 26] = 0.f; etab[tid*ESTR + 27] = 0.f;
  }

  if (tid == 0) {
    float w[10];
    for (int q = 0; q < 10; ++q) w[q] = wt[q];
    float la[35];
    float d2 = 1.f - w[9]*w[9];
    float d3 = 1.f - w[9]*w[9]*w[9];
    la[0]=1.f-w[0]; la[1]=w[0];
    la[2]=1.f; la[3]=1.f;
    la[4]=w[1]; la[5]=w[3]; la[6]=d2; la[7]=d3;
    la[8]=1.f; la[9]=1.f;
    la[10]=w[2]; la[11]=w[4]; la[12]=d2;
    la[13]=1.f; la[14]=1.f;
    la[15]=1.f-w[5]; la[16]=w[5];
    la[17]=1.f; la[18]=1.f; la[19]=1.f;
    la[20]=1.f; la[21]=1.f;
    la[22]=1.f; la[23]=1.f;
    la[24]=w[6]; la[25]=1.f-w[6];
    la[26]=1.f; la[27]=1.f;
    la[28]=w[7]; la[29]=1.f-w[7];
    la[30]=1.f; la[31]=1.f;
    la[32]=w[8]; la[33]=1.f-w[8];
    la[34]=1.f;
    const int rs[25] = {0,2,3,4,8,9,10,13,14,15,17,18,19,20,22,23,24,26,27,28,30,31,32,34,35};
    for (int r = 0; r < 24; ++r) {
      float mx = -1e30f;
      for (int e = rs[r]; e < rs[r+1]; ++e) mx = fmaxf(mx, la[e]);
      float sm = 0.f;
      for (int e = rs[r]; e < rs[r+1]; ++e) sm += expf(la[e] - mx);
      float inv = 1.0f / sm;
      for (int e = rs[r]; e < rs[r+1]; ++e) a35out[e] = expf(la[e] - mx) * inv;
    }
  }
}

// ------------------------------------------------------------------
__global__ __launch_bounds__(256) void k_build_ctx(
    const int* __restrict__ obs, unsigned char* __restrict__ ctx8)
{
  int i = (int)blockIdx.x * 256 + (int)threadIdx.x;
  int t = i & (TLEN - 1);
  int o0 = obs[i];
  int o1 = (t >= 1) ? obs[i-1] : 4;
  int o2 = (t >= 2) ? obs[i-2] : 4;
  ctx8[i] = (unsigned char)((o2*5 + o1)*4 + o0);
}

// ------------------------------------------------------------------
// Phase A: per (b, chunk, column) thread carries one column of the chunk
// transfer matrix, renormalized by column-max every 16 steps (log-scale
// accumulated to csb) to avoid f32 underflow over the chunk product.
// ------------------------------------------------------------------
template<int C, bool BF>
__global__ __launch_bounds__(256) void k_phaseA(
    const unsigned char* __restrict__ ctx8,
    const float* __restrict__ etab,
    const float* __restrict__ a35,
    void* __restrict__ mbuf,
    float* __restrict__ lsbuf,
    float* __restrict__ csb)
{
  constexpr int BPC = (BATCH * NST) / 256;   // blocks per chunk = 48
  __shared__ __align__(16) float et[NCTX * ESTR];
  for (int i = threadIdx.x; i < NCTX * ESTR; i += 256) et[i] = etab[i];
  float A[35];
  #pragma unroll
  for (int e = 0; e < 35; ++e) A[e] = a35[e];
  __syncthreads();

  const int L = TLEN / C;
  int c   = (int)blockIdx.x / BPC;
  int il  = ((int)blockIdx.x % BPC) * 256 + (int)threadIdx.x;
  int b   = il / NST;
  int col = il % NST;

  float m[NST];
  #pragma unroll
  for (int s = 0; s < NST; ++s) m[s] = (s == col) ? 1.0f : 0.0f;

  const unsigned char* cb = ctx8 + (size_t)b * TLEN;
  float ls  = 0.0f;   // shared E-lognorm sum (same for all cols) + ll0 on chunk 0
  float lsc = 0.0f;   // per-column log scale from renormalization
  int tstart = c * L;
  int nst = L;
  if (c == 0) {
    int ctx0 = cb[0];
    ls = logf(et[ctx0*ESTR]) + et[ctx0*ESTR + 24];   // ll0 = log B[0,4,4,obs0]
    tstart = 1; nst = L - 1;
  }

  for (int k = 0; k < nst; ++k) {
    int ctx = cb[tstart + k];
    const float4* ep = (const float4*)(&et[ctx * ESTR]);
    float ev[NST];
    #pragma unroll
    for (int j = 0; j < 6; ++j) {
      float4 q = ep[j];
      ev[4*j] = q.x; ev[4*j+1] = q.y; ev[4*j+2] = q.z; ev[4*j+3] = q.w;
    }
    ls += et[ctx*ESTR + 24];
    float R[NST];
    at_update(A, m, R);
    #pragma unroll
    for (int s = 0; s < NST; ++s) m[s] = R[s] * ev[s];

    if ((k & 15) == 15) {           // periodic column renorm: keep in f32 range
      float cmax = 0.f;
      #pragma unroll
      for (int s = 0; s < NST; ++s) cmax = fmaxf(cmax, m[s]);
      if (cmax > 0.f) {
        float r = 1.0f / cmax;
        lsc += logf(cmax);
        #pragma unroll
        for (int s = 0; s < NST; ++s) m[s] *= r;
      } else {
        lsc = -1e30f;               // dead column (exact zeros) — flag it
      }
    }
  }

  size_t base = ((size_t)(c*BATCH + b)) * (NST*NST);
  if (BF) {
    unsigned short* M = (unsigned short*)mbuf;
    #pragma unroll
    for (int s = 0; s < NST; ++s) M[base + s*NST + col] = f2bf(m[s]);
  } else {
    float* M = (float*)mbuf;
    #pragma unroll
    for (int s = 0; s < NST; ++s) M[base + s*NST + col] = m[s];
  }
  csb[(size_t)(c*BATCH + b)*NST + col] = lsc;
  if (col == 0) lsbuf[c*BATCH + b] = ls;
}

// ------------------------------------------------------------------
// Phase B: sequential scan over chunks; 32-lane group per batch element.
// Combines column log-scales in log-space; emits boundary f's and loglik.
// ------------------------------------------------------------------
template<int C, bool BF>
__global__ __launch_bounds__(256) void k_phaseB(
    const void* __restrict__ mbuf,
    const float* __restrict__ lsbuf,
    const float* __restrict__ csb,
    float* __restrict__ vb,
    float* __restrict__ alphas,
    float* __restrict__ llout)
{
  int i = (int)blockIdx.x * 256 + (int)threadIdx.x;
  int b = i >> 5;
  int g = i & 31;

  float v[NST];
  #pragma unroll
  for (int j = 0; j < NST; ++j) v[j] = (j == 0) ? 1.0f : 0.0f;

  if (g < NST) {
    vb[((size_t)b*C + 0)*NST + g] = (g == 0) ? 1.0f : 0.0f;
    alphas[(size_t)b*TLEN*NST + g] = (g == 0) ? 1.0f : 0.0f;   // t = 0 row
  }

  float ll = 0.0f;
  for (int c = 0; c < C; ++c) {
    float mr[NST];
    if (g < NST) {
      size_t rb = (((size_t)(c*BATCH + b))*NST + g) * NST;
      if (BF) {
        const unsigned short* M = (const unsigned short*)mbuf;
        const uint4* p = (const uint4*)(M + rb);
        uint4 u0 = p[0], u1 = p[1], u2 = p[2];
        unsigned uu[12] = {u0.x,u0.y,u0.z,u0.w, u1.x,u1.y,u1.z,u1.w, u2.x,u2.y,u2.z,u2.w};
        #pragma unroll
        for (int j = 0; j < 12; ++j) {
          mr[2*j]   = __uint_as_float(uu[j] << 16);
          mr[2*j+1] = __uint_as_float(uu[j] & 0xFFFF0000u);
        }
      } else {
        const float* Mf = (const float*)mbuf;
        const float4* p = (const float4*)(Mf + rb);
        #pragma unroll
        for (int j = 0; j < 6; ++j) {
          float4 q = p[j];
          mr[4*j] = q.x; mr[4*j+1] = q.y; mr[4*j+2] = q.z; mr[4*j+3] = q.w;
        }
      }
    } else {
      #pragma unroll
      for (int j = 0; j < NST; ++j) mr[j] = 0.f;
    }

    // log-space combine of column scales with current f
    float cs_g = (g < NST) ? csb[(size_t)(c*BATCH + b)*NST + g] : -1e30f;
    float vg   = (g < NST) ? v[g] : 0.f;
    float wg   = (g < NST && vg > 0.f && cs_g > -1e29f) ? cs_g + logf(vg) : -1e30f;
    float wm = wg;
    #pragma unroll
    for (int o = 1; o < 32; o <<= 1) wm = fmaxf(wm, __shfl_xor(wm, o, 32));
    float pg = (wg > -1e29f) ? expf(wg - wm) : 0.f;

    float p[NST];
    #pragma unroll
    for (int j = 0; j < NST; ++j) p[j] = __shfl(pg, j, 32);

    float nv = 0.f;
    #pragma unroll
    for (int j = 0; j < NST; ++j) nv += mr[j] * p[j];

    float z = nv;
    #pragma unroll
    for (int o = 1; o < 32; o <<= 1) z += __shfl_xor(z, o, 32);

    float fn = nv / z;               // e^{-wm} scale cancels in the ratio
    ll += logf(z) + wm + lsbuf[c*BATCH + b];

    #pragma unroll
    for (int j = 0; j < NST; ++j) v[j] = __shfl(fn, j, 32);

    if (g < NST && c + 1 < C) vb[((size_t)b*C + c + 1)*NST + g] = fn;
  }
  if (g == 0) llout[b] = ll;
}

// ------------------------------------------------------------------
// Phase C: replay normalized vector recurrence inside each chunk, stream alphas.
// ------------------------------------------------------------------
template<int C>
__global__ __launch_bounds__(256) void k_phaseC(
    const unsigned char* __restrict__ ctx8,
    const float* __restrict__ etab,
    const float* __restrict__ a35,
    const float* __restrict__ vb,
    float* __restrict__ alphas)
{
  __shared__ __align__(16) float et[NCTX * ESTR];
  for (int i = threadIdx.x; i < NCTX * ESTR; i += 256) et[i] = etab[i];
  float A[35];
  #pragma unroll
  for (int e = 0; e < 35; ++e) A[e] = a35[e];
  __syncthreads();

  const int L = TLEN / C;
  int i = (int)blockIdx.x * 256 + (int)threadIdx.x;
  int b = i / C;
  int c = i % C;

  float f[NST];
  {
    const float4* p = (const float4*)(vb + ((size_t)b*C + c) * NST);
    #pragma unroll
    for (int j = 0; j < 6; ++j) {
      float4 q = p[j];
      f[4*j] = q.x; f[4*j+1] = q.y; f[4*j+2] = q.z; f[4*j+3] = q.w;
    }
  }

  const unsigned char* cb = ctx8 + (size_t)b * TLEN;
  int t0 = c * L;
  for (int k = 0; k < L; ++k) {
    int t = t0 + k;
    if (t == 0) continue;      // t=0 row written by phase B
    int ctx = cb[t];
    const float4* ep = (const float4*)(&et[ctx * ESTR]);
    float ev[NST];
    #pragma unroll
    for (int j = 0; j < 6; ++j) {
      float4 q = ep[j];
      ev[4*j] = q.x; ev[4*j+1] = q.y; ev[4*j+2] = q.z; ev[4*j+3] = q.w;
    }
    float R[NST];
    at_update(A, f, R);
    float al[NST];
    #pragma unroll
    for (int s = 0; s < NST; ++s) al[s] = R[s] * ev[s];
    float z = tree_sum24(al);
    float zr = 1.0f / z;
    #pragma unroll
    for (int s = 0; s < NST; ++s) f[s] = al[s] * zr;

    float* op = alphas + ((size_t)b*TLEN + t) * NST;
    float4* o4 = (float4*)op;
    o4[0] = make_float4(f[0],  f[1],  f[2],  f[3]);
    o4[1] = make_float4(f[4],  f[5],  f[6],  f[7]);
    o4[2] = make_float4(f[8],  f[9],  f[10], f[11]);
    o4[3] = make_float4(f[12], f[13], f[14], f[15]);
    o4[4] = make_float4(f[16], f[17], f[18], f[19]);
    o4[5] = make_float4(f[20], f[21], f[22], f[23]);
  }
}

// ------------------------------------------------------------------
template<int C, bool BF>
static void run_pipeline(const unsigned char* ctx8, const float* etab, const float* a35,
                         void* mbuf, float* lsb, float* csb, float* vb,
                         float* alphas, float* llout, hipStream_t stream)
{
  constexpr int BPC = (BATCH * NST) / 256;
  k_phaseA<C, BF><<<C * BPC, 256, 0, stream>>>(ctx8, etab, a35, mbuf, lsb, csb);
  k_phaseB<C, BF><<<(BATCH * 32) / 256, 256, 0, stream>>>(mbuf, lsb, csb, vb, alphas, llout);
  k_phaseC<C><<<(BATCH * C) / 256, 256, 0, stream>>>(ctx8, etab, a35, vb, alphas);
}

extern "C" void kernel_launch(void* const* d_in, const int* in_sizes, int n_in,
                              void* d_out, int out_size, void* d_ws, size_t ws_size,
                              hipStream_t stream)
{
  (void)in_sizes; (void)n_in; (void)out_size;
  const int*   obs = (const int*)d_in[0];
  const float* wt  = (const float*)d_in[1];
  const float* we  = (const float*)d_in[2];
  // d_in[3] (init_kernel) is mathematically unused: softmax of 1 element == 1.

  float* out    = (float*)d_out;
  float* alphas = out;
  float* llout  = out + (size_t)BATCH * TLEN * NST;

  char* ws = (char*)d_ws;
  const size_t ETAB_OFF = 0;                                   // 11200 B
  const size_t A_OFF    = 12 * 1024;
  const size_t CTX_OFF  = 16 * 1024;                           // 1 MiB
  const size_t LS_OFF   = CTX_OFF + (size_t)BATCH * TLEN;      // 32*512*4
  const size_t CS_OFF   = LS_OFF + (size_t)32 * BATCH * 4;     // 32*512*24*4
  const size_t VB_OFF   = CS_OFF + (size_t)32 * BATCH * NST * 4;
  const size_t M_OFF    = VB_OFF + (size_t)BATCH * 32 * NST * 4;

  float* etab = (float*)(ws + ETAB_OFF);
  float* a35  = (float*)(ws + A_OFF);
  unsigned char* ctx8 = (unsigned char*)(ws + CTX_OFF);
  float* lsb  = (float*)(ws + LS_OFF);
  float* csb  = (float*)(ws + CS_OFF);
  float* vb   = (float*)(ws + VB_OFF);
  void*  mbuf = (void*)(ws + M_OFF);

  k_build_tables<<<1, 256, 0, stream>>>(wt, we, etab, a35);
  k_build_ctx<<<(BATCH * TLEN) / 256, 256, 0, stream>>>(obs, ctx8);

  const size_t needF32 = M_OFF + (size_t)32 * BATCH * NST * NST * 4;
  const size_t needBF  = M_OFF + (size_t)32 * BATCH * NST * NST * 2;

  if (ws_size >= needF32) {
    run_pipeline<32, false>(ctx8, etab, a35, mbuf, lsb, csb, vb, alphas, llout, stream);
  } else if (ws_size >= needBF) {
    run_pipeline<32, true>(ctx8, etab, a35, mbuf, lsb, csb, vb, alphas, llout, stream);
  } else {
    run_pipeline<8, true>(ctx8, etab, a35, mbuf, lsb, csb, vb, alphas, llout, stream);
  }
}